// Round 1
// baseline (2341.142 us; speedup 1.0000x reference)
//
#include <hip/hip_runtime.h>

// ---------------- constants ----------------
#define HD 1280          // hidden
#define ED 896           // expert intermediate
#define NR 64            // routed experts
#define NT 66            // + 2 shared pseudo-experts
#define TOPK 6
#define TK 2048          // tokens
#define EHD 1146880      // ED*HD per-expert weight elems
#define NSLOT 16384      // 2048*6 routed + 2*2048 shared
#define WKMAX 192        // sum ceil(cnt/128) <= 96+64 + 32 = 192

typedef unsigned short u16;
typedef unsigned int u32;
typedef short bf16x8 __attribute__((ext_vector_type(8)));
typedef float f32x4 __attribute__((ext_vector_type(4)));

__device__ __forceinline__ u16 f2b(float f) {
    union { float f; u32 u; } v; v.f = f;
    return (u16)((v.u + 0x7fffu + ((v.u >> 16) & 1u)) >> 16);
}
__device__ __forceinline__ float b2f(u16 h) {
    union { u32 u; float f; } v; v.u = ((u32)h) << 16;
    return v.f;
}

// ---------------- router: fp64 logits, top-6, counts; also x->bf16 ----------------
__global__ __launch_bounds__(64) void router_kernel(
    const float* __restrict__ x, const float* __restrict__ wr,
    u16* __restrict__ xb, int* __restrict__ cnt,
    int* __restrict__ eidx, int* __restrict__ epos, float* __restrict__ topw)
{
    int t = blockIdx.x;
    int lane = threadIdx.x;
    __shared__ double xs[HD];
    const float4* x4 = reinterpret_cast<const float4*>(x + (size_t)t * HD);
    for (int i = lane; i < HD / 4; i += 64) {
        float4 v = x4[i];
        xs[4*i+0] = v.x; xs[4*i+1] = v.y; xs[4*i+2] = v.z; xs[4*i+3] = v.w;
        unsigned long long pk = (unsigned long long)f2b(v.x)
                              | ((unsigned long long)f2b(v.y) << 16)
                              | ((unsigned long long)f2b(v.z) << 32)
                              | ((unsigned long long)f2b(v.w) << 48);
        reinterpret_cast<unsigned long long*>(xb + (size_t)t * HD)[i] = pk;
    }
    __syncthreads();
    const float* wrow = wr + (size_t)lane * HD;
    double acc = 0.0;
    for (int h = 0; h < HD; ++h) acc += xs[h] * (double)wrow[h];

    // iterative top-6 argmax (tie-break: lower index, matching lax.top_k)
    double cur = acc;
    double sel_l[TOPK]; int sel_i[TOPK];
    for (int k = 0; k < TOPK; ++k) {
        double bv = cur; int bi = lane;
        for (int o = 32; o > 0; o >>= 1) {
            double ov = __shfl_down(bv, o);
            int oi = __shfl_down(bi, o);
            if (ov > bv || (ov == bv && oi < bi)) { bv = ov; bi = oi; }
        }
        bv = __shfl(bv, 0); bi = __shfl(bi, 0);
        sel_l[k] = bv; sel_i[k] = bi;
        if (lane == bi) cur = -1e300;
    }
    if (lane < TOPK) {
        double m0 = sel_l[0], s = 0.0;
        for (int k = 0; k < TOPK; ++k) s += exp(sel_l[k] - m0);
        double w = exp(sel_l[lane] - m0) / s;
        int e = sel_i[lane];
        int pos = atomicAdd(&cnt[e], 1);
        eidx[t*TOPK + lane] = e;
        epos[t*TOPK + lane] = pos;
        topw[t*TOPK + lane] = (float)w;
    }
}

// ---------------- scan: offsets + work list ----------------
__global__ __launch_bounds__(128) void scan_kernel(int* cnt, int* off, int* wkl, int* nwork)
{
    __shared__ int s[128];
    int t = threadIdx.x;
    int c = 0;
    if (t < NR) c = cnt[t];
    if (t == 64 || t == 65) { c = TK; cnt[t] = TK; }
    s[t] = c;
    for (int d = 1; d < 128; d <<= 1) {
        __syncthreads();
        int add = (t >= d) ? s[t - d] : 0;
        __syncthreads();
        s[t] += add;
    }
    __syncthreads();
    if (t < NT) off[t] = s[t] - c;
    if (t == 65) off[66] = s[65];
    // second scan: work-groups of 128 tokens
    int ng = (t < NT) ? (c + 127) / 128 : 0;
    __syncthreads();
    s[t] = ng;
    for (int d = 1; d < 128; d <<= 1) {
        __syncthreads();
        int add = (t >= d) ? s[t - d] : 0;
        __syncthreads();
        s[t] += add;
    }
    __syncthreads();
    int base = s[t] - ng;
    for (int g = 0; g < ng; ++g) wkl[base + g] = (t << 8) | g;
    if (t == 127) *nwork = s[127];
}

// ---------------- scatter: slot lists ----------------
__global__ __launch_bounds__(256) void scatter_kernel(
    const int* __restrict__ eidx, const int* __restrict__ epos,
    const float* __restrict__ topw, const int* __restrict__ off,
    int* __restrict__ tok, float* __restrict__ wts, int* __restrict__ slot_of)
{
    int i = blockIdx.x * 256 + threadIdx.x;
    if (i >= TK * TOPK) return;
    int t = i / TOPK;
    int e = eidx[i];
    int s = off[e] + epos[i];
    tok[s] = t; wts[s] = topw[i]; slot_of[i] = s;
}

// ---------------- repack routed weights: [k][n][64] fp32 -> [e][n][k] bf16 ----------------
__global__ __launch_bounds__(256) void repack_routed(
    const float* __restrict__ src, u16* __restrict__ dst, int K, int Nf)
{
    long gid = (long)blockIdx.x * 256 + threadIdx.x;
    int e = (int)(gid & 63);
    long q = gid >> 6;
    int n = (int)(q % Nf);
    int kr = (int)(q / Nf);
    if (kr >= K / 32) return;
    const float* sp = src + ((long)kr * 32 * Nf + n) * 64 + e;
    long st = (long)Nf * 64;
    u32 wb[16];
#pragma unroll
    for (int i = 0; i < 16; ++i) {
        u32 lo = f2b(sp[(2*i) * st]);
        u32 hi = f2b(sp[(2*i+1) * st]);
        wb[i] = lo | (hi << 16);
    }
    u16* dp = dst + (long)e * Nf * K + (long)n * K + (long)kr * 32;
    uint4* d4 = reinterpret_cast<uint4*>(dp);
    d4[0] = make_uint4(wb[0],  wb[1],  wb[2],  wb[3]);
    d4[1] = make_uint4(wb[4],  wb[5],  wb[6],  wb[7]);
    d4[2] = make_uint4(wb[8],  wb[9],  wb[10], wb[11]);
    d4[3] = make_uint4(wb[12], wb[13], wb[14], wb[15]);
}

// ---------------- shared weights -> pseudo-expert slots 64/65 ----------------
__global__ __launch_bounds__(256) void repack_shared_gu(
    const float* __restrict__ src, u16* __restrict__ dst)
{
    long i = (long)blockIdx.x * 256 + threadIdx.x;  // per 8 elems
    if (i >= (long)(2*ED) * HD / 8) return;
    const float4* s4 = reinterpret_cast<const float4*>(src) + 2 * i;
    float4 a = s4[0], b = s4[1];
    uint4 w = make_uint4(f2b(a.x) | (f2b(a.y) << 16), f2b(a.z) | (f2b(a.w) << 16),
                         f2b(b.x) | (f2b(b.y) << 16), f2b(b.z) | (f2b(b.w) << 16));
    *reinterpret_cast<uint4*>(dst + (long)64 * EHD + 8 * i) = w;
}

__global__ __launch_bounds__(256) void repack_shared_dn(
    const float* __restrict__ src, u16* __restrict__ dst)
{
    int id = blockIdx.x * 256 + threadIdx.x;   // total HD*224
    if (id >= HD * 224) return;
    int h = id / 224, jc = id % 224;
    int c = jc / 112;
    int j = (jc % 112) * 8;
    const float4* s4 = reinterpret_cast<const float4*>(src + (long)h * (2*ED) + c * ED + j);
    float4 a = s4[0], b = s4[1];
    uint4 w = make_uint4(f2b(a.x) | (f2b(a.y) << 16), f2b(a.z) | (f2b(a.w) << 16),
                         f2b(b.x) | (f2b(b.y) << 16), f2b(b.z) | (f2b(b.w) << 16));
    *reinterpret_cast<uint4*>(dst + (long)(64 + c) * EHD + (long)h * ED + j) = w;
}

// ---------------- GU: gate+up GEMM + silu*up -> h1 (bf16) ----------------
// block = (work item e/mgroup, jt); 4 waves, each wave one 16-wide n-tile.
#define GU_ROW 1288   // 1280 + 8 pad -> 2-way-only LDS bank aliasing
__global__ __launch_bounds__(256) void gu_kernel(
    const u16* __restrict__ Gt, const u16* __restrict__ Ut,
    const u16* __restrict__ xb, const int* __restrict__ tok,
    const int* __restrict__ cnt, const int* __restrict__ off,
    const int* __restrict__ wkl, const int* __restrict__ nwork,
    u16* __restrict__ h1)
{
    if (blockIdx.x >= *nwork) return;
    int wke = wkl[blockIdx.x];
    int e = wke >> 8, mg = wke & 255;
    int c = cnt[e];
    int off_e = off[e];
    int jt = blockIdx.y;
    int wave = threadIdx.x >> 6, lane = threadIdx.x & 63;
    int q = lane >> 4, l16 = lane & 15;
    int n = jt * 64 + wave * 16 + l16;      // feature j in [0,896)
    __shared__ u16 As[16 * GU_ROW];
    const u16* gB = Gt + (size_t)e * EHD + (size_t)n * HD;
    const u16* uB = Ut + (size_t)e * EHD + (size_t)n * HD;
    int base_row = mg * 128;
    for (int mt = 0; mt < 8; ++mt) {
        int row0 = base_row + mt * 16;
        if (row0 >= c) break;
        __syncthreads();
        for (int idx = threadIdx.x; idx < 16 * 161; idx += 256) {
            int r = idx / 161, ck = idx % 161;
            uint4 v = make_uint4(0, 0, 0, 0);
            int row = row0 + r;
            if (row < c && ck < 160) {
                int tk = (e < NR) ? tok[off_e + row] : row;
                v = *reinterpret_cast<const uint4*>(xb + (size_t)tk * HD + ck * 8);
            }
            *reinterpret_cast<uint4*>(&As[r * GU_ROW + ck * 8]) = v;
        }
        __syncthreads();
        f32x4 ag = {0.f, 0.f, 0.f, 0.f}, au = {0.f, 0.f, 0.f, 0.f};
        const u16* ap = &As[l16 * GU_ROW + q * 8];
        for (int kw = 0; kw < HD / 32; ++kw) {
            bf16x8 a  = *reinterpret_cast<const bf16x8*>(ap + kw * 32);
            bf16x8 bg = *reinterpret_cast<const bf16x8*>(gB + kw * 32 + q * 8);
            bf16x8 bu = *reinterpret_cast<const bf16x8*>(uB + kw * 32 + q * 8);
            ag = __builtin_amdgcn_mfma_f32_16x16x32_bf16(a, bg, ag, 0, 0, 0);
            au = __builtin_amdgcn_mfma_f32_16x16x32_bf16(a, bu, au, 0, 0, 0);
        }
#pragma unroll
        for (int i = 0; i < 4; ++i) {
            int row = row0 + q * 4 + i;
            if (row < c) {
                float g = ag[i];
                float hv = g / (1.f + __expf(-g)) * au[i];
                h1[(size_t)(off_e + row) * ED + n] = f2b(hv);
            }
        }
    }
}

// ---------------- DN: down GEMM, apply routing weight -> h2 (fp32) ----------------
#define DN_ROW 904    // 896 + 8 pad
__global__ __launch_bounds__(256) void dn_kernel(
    const u16* __restrict__ Dt, const u16* __restrict__ h1,
    const float* __restrict__ wts, const int* __restrict__ cnt,
    const int* __restrict__ off, const int* __restrict__ wkl,
    const int* __restrict__ nwork, float* __restrict__ h2)
{
    if (blockIdx.x >= *nwork) return;
    int wke = wkl[blockIdx.x];
    int e = wke >> 8, mg = wke & 255;
    int c = cnt[e];
    int off_e = off[e];
    int ht = blockIdx.y;
    int wave = threadIdx.x >> 6, lane = threadIdx.x & 63;
    int q = lane >> 4, l16 = lane & 15;
    int n = ht * 64 + wave * 16 + l16;      // h in [0,1280)
    __shared__ u16 As[16 * DN_ROW];
    const u16* bp = Dt + (size_t)e * EHD + (size_t)n * ED;
    int base_row = mg * 128;
    for (int mt = 0; mt < 8; ++mt) {
        int row0 = base_row + mt * 16;
        if (row0 >= c) break;
        __syncthreads();
        for (int idx = threadIdx.x; idx < 16 * 113; idx += 256) {
            int r = idx / 113, ck = idx % 113;
            uint4 v = make_uint4(0, 0, 0, 0);
            int row = row0 + r;
            if (row < c && ck < 112)
                v = *reinterpret_cast<const uint4*>(h1 + (size_t)(off_e + row) * ED + ck * 8);
            *reinterpret_cast<uint4*>(&As[r * DN_ROW + ck * 8]) = v;
        }
        __syncthreads();
        f32x4 acc = {0.f, 0.f, 0.f, 0.f};
        const u16* ap = &As[l16 * DN_ROW + q * 8];
        for (int kw = 0; kw < ED / 32; ++kw) {
            bf16x8 a = *reinterpret_cast<const bf16x8*>(ap + kw * 32);
            bf16x8 b = *reinterpret_cast<const bf16x8*>(bp + kw * 32 + q * 8);
            acc = __builtin_amdgcn_mfma_f32_16x16x32_bf16(a, b, acc, 0, 0, 0);
        }
#pragma unroll
        for (int i = 0; i < 4; ++i) {
            int row = row0 + q * 4 + i;
            if (row < c) {
                float wv = (e < NR) ? wts[off_e + row] : 1.0f;
                h2[(size_t)(off_e + row) * HD + n] = acc[i] * wv;
            }
        }
    }
}

// ---------------- gather: 6 routed slots + 2 shared slots ----------------
__global__ __launch_bounds__(256) void gather_kernel(
    const float* __restrict__ h2, const int* __restrict__ slot_of,
    float* __restrict__ out)
{
    int t = blockIdx.x;
    int s0 = slot_of[t*TOPK+0], s1 = slot_of[t*TOPK+1], s2 = slot_of[t*TOPK+2];
    int s3 = slot_of[t*TOPK+3], s4 = slot_of[t*TOPK+4], s5 = slot_of[t*TOPK+5];
    for (int h = threadIdx.x; h < HD; h += 256) {
        float acc = h2[(size_t)(12288 + t) * HD + h] + h2[(size_t)(14336 + t) * HD + h];
        acc += h2[(size_t)s0 * HD + h];
        acc += h2[(size_t)s1 * HD + h];
        acc += h2[(size_t)s2 * HD + h];
        acc += h2[(size_t)s3 * HD + h];
        acc += h2[(size_t)s4 * HD + h];
        acc += h2[(size_t)s5 * HD + h];
        out[(size_t)t * HD + h] = acc;
    }
}

// ---------------- launch ----------------
extern "C" void kernel_launch(void* const* d_in, const int* in_sizes, int n_in,
                              void* d_out, int out_size, void* d_ws, size_t ws_size,
                              hipStream_t stream)
{
    const float* x   = (const float*)d_in[0];
    const float* wr  = (const float*)d_in[1];
    const float* gpe = (const float*)d_in[2];
    const float* upe = (const float*)d_in[3];
    const float* dpe = (const float*)d_in[4];
    const float* wsg = (const float*)d_in[5];
    const float* wsu = (const float*)d_in[6];
    const float* wsd = (const float*)d_in[7];
    float* out = (float*)d_out;

    char* p = (char*)d_ws;
    auto alloc = [&](size_t b) -> void* {
        void* r = (void*)p;
        p += (b + 255) & ~(size_t)255;
        return r;
    };
    u16* Gt = (u16*)alloc((size_t)NT * EHD * 2);
    u16* Ut = (u16*)alloc((size_t)NT * EHD * 2);
    u16* Dt = (u16*)alloc((size_t)NT * EHD * 2);
    u16* xb = (u16*)alloc((size_t)TK * HD * 2);
    u16* h1 = (u16*)alloc((size_t)NSLOT * ED * 2);
    float* h2 = (float*)alloc((size_t)NSLOT * HD * 4);
    int*   tok     = (int*)alloc(NSLOT * 4);
    float* wts     = (float*)alloc(NSLOT * 4);
    int*   slot_of = (int*)alloc(TK * TOPK * 4);
    int*   eidx    = (int*)alloc(TK * TOPK * 4);
    int*   epos    = (int*)alloc(TK * TOPK * 4);
    float* topw    = (float*)alloc(TK * TOPK * 4);
    int* cnt   = (int*)alloc(512);
    int* off   = (int*)alloc(512);
    int* wkl   = (int*)alloc(1024);
    int* nwork = (int*)alloc(256);

    hipMemsetAsync(cnt, 0, 512, stream);
    router_kernel<<<TK, 64, 0, stream>>>(x, wr, xb, cnt, eidx, epos, topw);
    scan_kernel<<<1, 128, 0, stream>>>(cnt, off, wkl, nwork);
    scatter_kernel<<<(TK * TOPK + 255) / 256, 256, 0, stream>>>(eidx, epos, topw, off, tok, wts, slot_of);
    // routed weight repacks: 64*Nf*(K/32) threads each = 8960 blocks
    repack_routed<<<8960, 256, 0, stream>>>(gpe, Gt, HD, ED);
    repack_routed<<<8960, 256, 0, stream>>>(upe, Ut, HD, ED);
    repack_routed<<<8960, 256, 0, stream>>>(dpe, Dt, ED, HD);
    repack_shared_gu<<<1120, 256, 0, stream>>>(wsg, Gt);
    repack_shared_gu<<<1120, 256, 0, stream>>>(wsu, Ut);
    repack_shared_dn<<<1120, 256, 0, stream>>>(wsd, Dt);
    gu_kernel<<<dim3(WKMAX, ED / 64), 256, 0, stream>>>(Gt, Ut, xb, tok, cnt, off, wkl, nwork, h1);
    dn_kernel<<<dim3(WKMAX, HD / 64), 256, 0, stream>>>(Dt, h1, wts, cnt, off, wkl, nwork, h2);
    gather_kernel<<<TK, 256, 0, stream>>>(h2, slot_of, out);
}